// Round 4
// baseline (22977.806 us; speedup 1.0000x reference)
//
#include <hip/hip_runtime.h>

typedef _Float16 half8 __attribute__((ext_vector_type(8)));
typedef float f32x4 __attribute__((ext_vector_type(4)));

#define MFMA(a,b,c) __builtin_amdgcn_mfma_f32_16x16x32_f16((a),(b),(c),0,0,0)

#define WS_ETAB (4160*1024)            // packed weights: 4160 tiles x 1KB
#define WS_H0   (WS_ETAB + 64*512*4)   // + Etab 128KB; h0w 2MB

// ---- async global->LDS, 16B/lane ----
__device__ __forceinline__ void gll16(const void* g, void* l){
  __builtin_amdgcn_global_load_lds(
      (const __attribute__((address_space(1))) void*)g,
      (__attribute__((address_space(3))) void*)l, 16, 0, 0);
}

// =============== weight packing: per-wave contiguous consumption order ===============
// regions (tile = 1KB = 16 outputs x 32 K, f16):
//  X  [0,256):     w*32 + i*8 + ks                     (W_in[0:256,:])
//  B  [256,3328):  256 + w*384 + i*96 + (kc*6+acc)*4+q (W_ih^T/W_hh^T; ks=kc*4+q)
//  D  [3328,3840): 3328 + w*64 + i*16 + ks             (W_o1[0:512,:])
//  C  [3840,4096): 3840 + w*32 + i*8 + ks              (W_o1[512:768,:])
//  E  [4096,4160): 4096 + w*16 + ks                    (W_o2)
__global__ void pack_k(const float* __restrict__ W_in, const float* __restrict__ W_ih,
                       const float* __restrict__ W_hh, const float* __restrict__ W_o1,
                       const float* __restrict__ W_o2, _Float16* __restrict__ pk)
{
  int ti = blockIdx.x, lane = threadIdx.x;
  int lo = lane & 15;
  int sel = 0, n = 0, ks = 0;
  if (ti < 256){
    int w = ti >> 5, r = ti & 31, i = r >> 3; ks = r & 7;
    n = (w*4 + i)*16 + lo; sel = 0;
  } else if (ti < 3328){
    int r = ti - 256, w = r/384, r2 = r%384, i = r2/96, r3 = r2%96;
    int cidx = r3 >> 2, q = r3 & 3, kc = cidx/6, acc = cidx%6;
    ks = kc*4 + q;
    int nn = (w*4 + i)*16 + lo;
    if (acc < 3){ n = acc*512 + nn; sel = 1; }
    else        { n = (acc-3)*512 + nn; sel = 2; }
  } else if (ti < 3840){
    int r = ti - 3328, w = r >> 6, r2 = r & 63, i = r2 >> 4; ks = r2 & 15;
    n = (w*4 + i)*16 + lo; sel = 3;
  } else if (ti < 4096){
    int r = ti - 3840, w = r >> 5, r2 = r & 31, i = r2 >> 3; ks = r2 & 7;
    n = (w*4 + i)*16 + lo; sel = 4;
  } else {
    int r = ti - 4096, w = r >> 4; ks = r & 15;
    n = w*16 + lo; sel = 5;
  }
  int kb = ks*32 + (lane >> 4)*8;
  half8 v;
  #pragma unroll
  for (int e = 0; e < 8; e++){
    int k = kb + e; float f;
    if      (sel == 0) f = W_in[k*512 + n];
    else if (sel == 1) f = W_ih[n*512 + k];
    else if (sel == 2) f = W_hh[n*512 + k];
    else if (sel == 3) f = W_o1[k*512 + n];
    else if (sel == 4) f = W_o1[(512 + k)*512 + n];
    else               f = W_o2[k*64 + n];
    v[e] = (_Float16)f;
  }
  *(half8*)(pk + (long)ti*512 + lane*8) = v;
}

// ---------------- Etab[e][j] = E[e,:] @ W_in[256:512, j] + b_in[j] ----------------
__global__ void etab_k(const float* __restrict__ E, const float* __restrict__ W_in,
                       const float* __restrict__ b_in, float* __restrict__ Etab)
{
  int e = blockIdx.x, tid = threadIdx.x;
  __shared__ float er[256];
  if (tid < 256) er[tid] = E[e*256 + tid];
  __syncthreads();
  for (int j = tid; j < 512; j += 256){
    float acc = b_in[j];
    for (int k = 0; k < 256; k++) acc += er[k] * W_in[(256 + k)*512 + j];
    Etab[e*512 + j] = acc;
  }
}

// ---------------- h0 = tanh([ctx_mean, hist_emb] @ W_init + b_init), fp32 ----------------
__global__ __launch_bounds__(512) void h0_k(const float* __restrict__ ctx,
    const int* __restrict__ bh, const float* __restrict__ E,
    const float* __restrict__ W_init, const float* __restrict__ b_init,
    float* __restrict__ h0w)
{
  int b0 = blockIdx.x * 16, tid = threadIdx.x;
  __shared__ float cat[16][512];
  int c = tid & 255, rh = tid >> 8;
  for (int rr = 0; rr < 8; rr++){
    int r2 = rh*8 + rr;
    const float* p = ctx + ((b0 + r2)*128)*256 + c;
    float acc = 0.f;
    for (int t = 0; t < 128; t++) acc += p[t*256];
    cat[r2][c] = acc * (1.f/128.f);
    float s = 0.f;
    #pragma unroll
    for (int hh = 0; hh < 8; hh++){
      int e = bh[(b0 + r2)*8 + hh];
      s += E[e*256 + c];
    }
    cat[r2][256 + c] = s * 0.125f;
  }
  __syncthreads();
  int j = tid;
  float acc[16];
  #pragma unroll
  for (int r2 = 0; r2 < 16; r2++) acc[r2] = b_init[j];
  for (int k = 0; k < 512; k++){
    float wv = W_init[k*512 + j];
    #pragma unroll
    for (int r2 = 0; r2 < 16; r2++) acc[r2] += cat[r2][k] * wv;
  }
  #pragma unroll
  for (int r2 = 0; r2 < 16; r2++) h0w[(b0 + r2)*512 + j] = tanhf(acc[r2]);
}

// ================= main persistent scan: 64 WGs x 512 thr, 16 rows each =================
#define AFRAG(buf, base, ks) (*(const half8*)((const char*)(buf) + ((((base) + (ks)*64)) ^ aswz)))
#define WSTORE(buf, row, j, val) \
  *(_Float16*)((char*)(buf) + ((((row)*1024 + (j)*2)) ^ ((((row)&7))<<4))) = (_Float16)(val)

#define WAITC do{ asm volatile("s_waitcnt vmcnt(8)" ::: "memory"); \
                  __builtin_amdgcn_sched_barrier(0); }while(0)
#define DRAIN do{ asm volatile("s_waitcnt vmcnt(0)" ::: "memory"); \
                  __builtin_amdgcn_sched_barrier(0); }while(0)
#define SBAR  do{ asm volatile("s_waitcnt lgkmcnt(0)" ::: "memory"); \
                  __builtin_amdgcn_s_barrier(); \
                  asm volatile("" ::: "memory"); }while(0)

#define ISSUE_CHUNK(j_) do{                                                     \
    const int j__ = (j_);                                                       \
    const char* src_;                                                           \
    if (j__ < 8)        src_ = pkb + (((long)((w<<5) + (j__<<2))) << 10);       \
    else if (j__ < 104) src_ = pkb + (((long)(256 + w*384 + ((j__-8)<<2))) << 10);\
    else if (j__ < 128){ const int r_ = j__-104, i_ = r_/6, c_ = r_%6;          \
        src_ = (c_<4) ? pkb + (((long)(3328 + (w<<6) + (i_<<4) + (c_<<2))) << 10) \
                      : pkb + (((long)(3840 + (w<<5) + (i_<<3) + ((c_-4)<<2))) << 10);} \
    else                src_ = pkb + (((long)(4096 + ((w&3)<<4) + ((j__-128)<<2))) << 10); \
    char* dst_ = ring + (((w*3) + (j__%3))<<12);                                \
    gll16(src_ +    0 + (lane<<4), dst_ +    0);                                \
    gll16(src_ + 1024 + (lane<<4), dst_ + 1024);                                \
    gll16(src_ + 2048 + (lane<<4), dst_ + 2048);                                \
    gll16(src_ + 3072 + (lane<<4), dst_ + 3072);                                \
  }while(0)

#define ISSUE_NEXT(j_) do{ __builtin_amdgcn_sched_barrier(0);                   \
    ISSUE_CHUNK((((j_)+3) >= 132) ? ((j_)+3-132) : ((j_)+3)); }while(0)

#define RINGF(j_, q_) (*(const half8*)(ring + (((w*3) + ((j_)%3))<<12) + ((q_)<<10) + (lane<<4)))

__global__ __launch_bounds__(512) void main_k(
    const _Float16* __restrict__ pk, const float* __restrict__ Etab,
    const float* __restrict__ h0w, const float* __restrict__ ctx,
    const int* __restrict__ bh, const float* __restrict__ b_ih,
    const float* __restrict__ b_hh, const float* __restrict__ lng,
    const float* __restrict__ lnb, const float* __restrict__ b_o1,
    const float* __restrict__ b_o2, float* __restrict__ out)
{
  const int g = blockIdx.x, tid = threadIdx.x;
  const int w = tid >> 6, lane = tid & 63, lo = lane & 15, hi = lane >> 4;
  const int r0 = g*16;

  extern __shared__ __align__(16) char dynring[];
  char* ring = dynring;                       // 8 waves x 3 slots x 4KB = 96KB

  __shared__ __align__(16) _Float16 hbuf0[16*512]; // h / hn (ping-pong)
  __shared__ __align__(16) _Float16 hbuf1[16*512];
  __shared__ __align__(16) _Float16 xh_s [16*512]; // x, then hidden
  __shared__ __align__(16) _Float16 c_s  [16*256]; // ctx_t f16
  __shared__ float lg_s[16*64];
  __shared__ float stats[8][4][4][2];
  __shared__ float murs[16][2];
  __shared__ int   pb[16];

  float bcr[4], bcz[4], bin_[4], bhn[4], bo1v[4], lngv[4], lnbv[4];
  #pragma unroll
  for (int i = 0; i < 4; i++){
    int j = w*64 + i*16 + lo;
    bcr[i] = b_ih[j]     + b_hh[j];
    bcz[i] = b_ih[512+j] + b_hh[512+j];
    bin_[i]= b_ih[1024+j];
    bhn[i] = b_hh[1024+j];
    bo1v[i]= b_o1[j]; lngv[i]= lng[j]; lnbv[i]= lnb[j];
  }
  const float bo2v = (w < 4) ? b_o2[w*16 + lo] : 0.f;

  float hreg[4][4];
  #pragma unroll
  for (int i = 0; i < 4; i++)
    #pragma unroll
    for (int rr = 0; rr < 4; rr++)
      hreg[i][rr] = h0w[(r0 + hi*4 + rr)*512 + w*64 + i*16 + lo];

  // stage h0 -> hbuf0 (f16, swizzled)
  #pragma unroll
  for (int c2 = 0; c2 < 2; c2++){
    int ch = tid*2 + c2, rr = ch >> 6, c8 = ch & 63;
    const float* p = h0w + (r0 + rr)*512 + c8*8;
    half8 v;
    #pragma unroll
    for (int e = 0; e < 8; e++) v[e] = (_Float16)p[e];
    *(half8*)((char*)hbuf0 + (((rr*1024 + c8*16)) ^ ((rr&7)<<4))) = v;
  }
  if (tid < 16) pb[tid] = bh[(r0 + tid)*8 + 7];
  __syncthreads();

  const int aswz  = (lo & 7) << 4;
  const int abase = lo*1024 + hi*16;
  const int cbase = lo*512  + hi*16;
  const char* pkb = (const char*)pk;

  ISSUE_CHUNK(0); ISSUE_CHUNK(1); ISSUE_CHUNK(2);

  #pragma unroll 1
  for (int t = 0; t < 128; t++){
    _Float16* hbr = (t & 1) ? hbuf1 : hbuf0;   // h_{t-1} in B; hn in D
    _Float16* hbw = (t & 1) ? hbuf0 : hbuf1;   // new h for t+1

    // ---- A1: ctx loads + Etab gathers, then the one per-step drain ----
    float et[4][4];
    {
      int rr0 = tid >> 5, c8 = tid & 31;
      const float* cp = ctx + (((long)(r0 + rr0)*128 + t)*256) + c8*8;
      float cv[8];
      #pragma unroll
      for (int e = 0; e < 8; e++) cv[e] = cp[e];
      int pbv[4];
      #pragma unroll
      for (int rr = 0; rr < 4; rr++) pbv[rr] = pb[hi*4 + rr];
      #pragma unroll
      for (int rr = 0; rr < 4; rr++)
        #pragma unroll
        for (int i = 0; i < 4; i++)
          et[i][rr] = Etab[pbv[rr]*512 + w*64 + i*16 + lo];
      DRAIN;                               // etab+ctx done; chunks 0..2 landed
      half8 v;
      #pragma unroll
      for (int e = 0; e < 8; e++) v[e] = (_Float16)cv[e];
      *(half8*)((char*)c_s + (((rr0*512 + c8*16)) ^ ((rr0&7)<<4))) = v;
    }
    SBAR;

    // ---- A2: x = relu(ctx @ W_in_top + Etab[pb]) ----  chunks j=0..7
    #pragma unroll
    for (int i = 0; i < 4; i++){
      f32x4 accx = {0.f,0.f,0.f,0.f};
      #pragma unroll
      for (int jj = 0; jj < 2; jj++){
        const int j = i*2 + jj;
        WAITC;
        #pragma unroll
        for (int q = 0; q < 4; q++)
          accx = MFMA(AFRAG(c_s, cbase, jj*4 + q), RINGF(j, q), accx);
        ISSUE_NEXT(j);
      }
      #pragma unroll
      for (int rr = 0; rr < 4; rr++){
        int row = hi*4 + rr, jc = w*64 + i*16 + lo;
        WSTORE(xh_s, row, jc, fmaxf(accx[rr] + et[i][rr], 0.f));
      }
    }
    SBAR;

    // ---- B: gi/gh + GRU gates ----  chunks j=8..103
    {
      float srow[4] = {0,0,0,0}, sqrow[4] = {0,0,0,0};
      #pragma unroll
      for (int i = 0; i < 4; i++){
        f32x4 a[6];
        const f32x4 z4 = {0.f,0.f,0.f,0.f};
        #pragma unroll
        for (int x = 0; x < 6; x++) a[x] = z4;
        #pragma unroll
        for (int kc = 0; kc < 4; kc++){
          half8 ax[4], ah[4];
          #pragma unroll
          for (int q = 0; q < 4; q++){
            ax[q] = AFRAG(xh_s, abase, kc*4 + q);
            ah[q] = AFRAG(hbr,  abase, kc*4 + q);
          }
          #pragma unroll
          for (int acc = 0; acc < 6; acc++){
            const int j = 8 + i*24 + kc*6 + acc;
            WAITC;
            #pragma unroll
            for (int q = 0; q < 4; q++)
              a[acc] = MFMA((acc < 3) ? ax[q] : ah[q], RINGF(j, q), a[acc]);
            ISSUE_NEXT(j);
          }
        }
        #pragma unroll
        for (int rr = 0; rr < 4; rr++){
          float rg = 1.f/(1.f + __expf(-(a[0][rr] + a[3][rr] + bcr[i])));
          float zg = 1.f/(1.f + __expf(-(a[1][rr] + a[4][rr] + bcz[i])));
          float aa = (a[2][rr] + bin_[i]) + rg*(a[5][rr] + bhn[i]);
          float ea = __expf(-2.f*fabsf(aa));
          float th = (1.f - ea)/(1.f + ea);
          float ng = (aa < 0.f) ? -th : th;
          float hv = (1.f - zg)*ng + zg*hreg[i][rr];
          hreg[i][rr] = hv;
          srow[rr] += hv; sqrow[rr] += hv*hv;
        }
      }
      #pragma unroll
      for (int d = 1; d < 16; d <<= 1){
        #pragma unroll
        for (int rr = 0; rr < 4; rr++){
          srow[rr]  += __shfl_xor(srow[rr],  d);
          sqrow[rr] += __shfl_xor(sqrow[rr], d);
        }
      }
      if (lo == 0){
        #pragma unroll
        for (int rr = 0; rr < 4; rr++){
          stats[w][hi][rr][0] = srow[rr];
          stats[w][hi][rr][1] = sqrow[rr];
        }
      }
    }
    SBAR;
    if (w == 0 && lane < 16){
      float s = 0.f, q = 0.f;
      #pragma unroll
      for (int ww = 0; ww < 8; ww++){
        s += stats[ww][lane>>2][lane&3][0];
        q += stats[ww][lane>>2][lane&3][1];
      }
      float mu = s*(1.f/512.f);
      float var = q*(1.f/512.f) - mu*mu;
      murs[lane][0] = mu;
      murs[lane][1] = rsqrtf(var + 1e-5f);
    }
    SBAR;

    // ---- C: write new h -> hbw, layernorm(h) -> hbr (h_{t-1} dead) ----
    #pragma unroll
    for (int rr = 0; rr < 4; rr++){
      int row = hi*4 + rr;
      float mu = murs[row][0], rs = murs[row][1];
      #pragma unroll
      for (int i = 0; i < 4; i++){
        int jc = w*64 + i*16 + lo;
        float hv = hreg[i][rr];
        WSTORE(hbw, row, jc, hv);
        WSTORE(hbr, row, jc, (hv - mu)*rs*lngv[i] + lnbv[i]);
      }
    }
    SBAR;

    // ---- D: hidden = relu(hn @ W_o1_top + ctx @ W_o1_bot + b_o1) ---- j=104..127
    #pragma unroll
    for (int i = 0; i < 4; i++){
      f32x4 acc = {0.f,0.f,0.f,0.f};
      #pragma unroll
      for (int c = 0; c < 6; c++){
        const int j = 104 + i*6 + c;
        WAITC;
        #pragma unroll
        for (int q = 0; q < 4; q++){
          half8 a = (c < 4) ? AFRAG(hbr, abase, c*4 + q)
                            : AFRAG(c_s, cbase, (c-4)*4 + q);
          acc = MFMA(a, RINGF(j, q), acc);
        }
        ISSUE_NEXT(j);
      }
      #pragma unroll
      for (int rr = 0; rr < 4; rr++){
        int row = hi*4 + rr, jc = w*64 + i*16 + lo;
        WSTORE(xh_s, row, jc, fmaxf(acc[rr] + bo1v[i], 0.f));
      }
    }
    SBAR;

    // ---- E: logits = hidden @ W_o2 + b_o2 ---- j=128..131 (w>=4: keep cadence)
    if (w < 4){
      f32x4 acc = {0.f,0.f,0.f,0.f};
      #pragma unroll
      for (int c = 0; c < 4; c++){
        const int j = 128 + c;
        WAITC;
        #pragma unroll
        for (int q = 0; q < 4; q++)
          acc = MFMA(AFRAG(xh_s, abase, c*4 + q), RINGF(j, q), acc);
        ISSUE_NEXT(j);
      }
      #pragma unroll
      for (int rr = 0; rr < 4; rr++){
        int row = hi*4 + rr, jc = w*16 + lo;
        lg_s[row*64 + jc] = acc[rr] + bo2v;
      }
    } else {
      #pragma unroll
      for (int c = 0; c < 4; c++){
        const int j = 128 + c;
        WAITC;
        ISSUE_NEXT(j);
      }
    }
    SBAR;

    // ---- F: out store + argmax (first-max tie rule), 2 rows per wave ----
    #pragma unroll
    for (int sub = 0; sub < 2; sub++){
      int r2 = w*2 + sub;
      float v = lg_s[r2*64 + lane];
      out[(((long)(r0 + r2))*128 + t)*64 + lane] = v;
      int idx = lane;
      #pragma unroll
      for (int d = 1; d < 64; d <<= 1){
        float ov = __shfl_xor(v, d);
        int oi = __shfl_xor(idx, d);
        if (ov > v || (ov == v && oi < idx)){ v = ov; idx = oi; }
      }
      if (lane == 0) pb[r2] = idx;
    }
    SBAR;
  }
}

extern "C" void kernel_launch(void* const* d_in, const int* in_sizes, int n_in,
                              void* d_out, int out_size, void* d_ws, size_t ws_size,
                              hipStream_t stream)
{
  const float* ctx    = (const float*)d_in[0];
  const int*   bh     = (const int*)d_in[1];
  const float* E      = (const float*)d_in[2];
  const float* W_in   = (const float*)d_in[3];
  const float* b_in   = (const float*)d_in[4];
  const float* W_init = (const float*)d_in[5];
  const float* b_init = (const float*)d_in[6];
  const float* W_ih   = (const float*)d_in[7];
  const float* W_hh   = (const float*)d_in[8];
  const float* b_ih   = (const float*)d_in[9];
  const float* b_hh   = (const float*)d_in[10];
  const float* ln_g   = (const float*)d_in[11];
  const float* ln_b   = (const float*)d_in[12];
  const float* W_o1   = (const float*)d_in[13];
  const float* b_o1   = (const float*)d_in[14];
  const float* W_o2   = (const float*)d_in[15];
  const float* b_o2   = (const float*)d_in[16];
  float* out = (float*)d_out;

  _Float16* pk   = (_Float16*)d_ws;
  float*    Etab = (float*)((char*)d_ws + WS_ETAB);
  float*    h0w  = (float*)((char*)d_ws + WS_H0);

  (void)hipFuncSetAttribute((const void*)main_k,
      hipFuncAttributeMaxDynamicSharedMemorySize, 96*1024);

  hipLaunchKernelGGL(pack_k, dim3(4160), dim3(64), 0, stream, W_in, W_ih, W_hh, W_o1, W_o2, pk);
  hipLaunchKernelGGL(etab_k, dim3(64), dim3(256), 0, stream, E, W_in, b_in, Etab);
  hipLaunchKernelGGL(h0_k, dim3(64), dim3(512), 0, stream, ctx, bh, E, W_init, b_init, h0w);
  hipLaunchKernelGGL(main_k, dim3(64), dim3(512), 96*1024, stream, pk, Etab, h0w, ctx, bh,
                     b_ih, b_hh, ln_g, ln_b, b_o1, b_o2, out);
}